// Round 4
// baseline (205.483 us; speedup 1.0000x reference)
//
#include <hip/hip_runtime.h>

#define BB 4
#define CIN 3
#define HH 512
#define WW 512
#define KK 9
#define COUT 3
#define HO 510
#define WO 510
#define HW (HH * WW)
#define HOWO (HO * WO)

#define XT_BYTES ((size_t)BB * HH * WW * 4 * sizeof(float))

__device__ __forceinline__ float comp3(const float4& v, int c) {
    return c == 0 ? v.x : (c == 1 ? v.y : v.z);
}

// ---------------- kernel 1: NCHW -> NHW4 repack ----------------
__global__ __launch_bounds__(256) void repack_nhwc(
    const float* __restrict__ x, float4* __restrict__ xT)
{
    const int idx = blockIdx.x * blockDim.x + threadIdx.x;
    const int total = BB * HH * WW;
    if (idx >= total) return;
    const int b = idx / HW;
    const int p = idx - b * HW;
    const float* xb = x + (size_t)b * CIN * HW;
    float4 v;
    v.x = xb[0 * HW + p];
    v.y = xb[1 * HW + p];
    v.z = xb[2 * HW + p];
    v.w = 0.f;
    xT[idx] = v;
}

// ---------------- kernel 2: fused conv1 + bilinear gather + conv2 ----------
// One thread = 2x2 output block. Weights packed as float4 pairs in LDS:
// one broadcast ds_read_b128 feeds 16 FMAs.
__global__ __launch_bounds__(256, 3) void deform_fused2(
    const float4* __restrict__ xT,  // [B][H][W] (3ch + pad)
    const float* __restrict__ w1,   // [18][3][3][3]
    const float* __restrict__ b1,   // [18]
    const float* __restrict__ w2,   // [3][3][3][3]
    const float* __restrict__ b2,   // [3]
    float* __restrict__ out)        // [B][3][HO][WO]
{
    // s_w4[k*14+g] = (wy[2g], wx[2g], wy[2g+1], wx[2g+1]) for tap k,
    // t2 = r*9 + s*3 + c (t2 = 27 padded with zeros)
    __shared__ float4 s_w4[KK * 14];
    __shared__ float s_b[18];
    __shared__ float s_w2[KK * 12];  // [k][12], first 9 = o*3+c
    __shared__ float s_b2[COUT];

    for (int t = threadIdx.x; t < KK * 56; t += 256) {
        const int k = t / 56;
        const int rem = t % 56;
        const int g = rem >> 2;
        const int comp = rem & 3;
        const int t2 = 2 * g + (comp >> 1);
        const int w = comp & 1;
        float val = 0.f;
        if (t2 < 27) {
            const int r = t2 / 9;
            const int s = (t2 % 9) / 3;
            const int c = t2 % 3;
            val = w1[(2 * k + w) * 27 + c * 9 + r * 3 + s];
        }
        reinterpret_cast<float*>(s_w4)[t] = val;
    }
    for (int t = threadIdx.x; t < KK * 12; t += 256) {
        const int k = t / 12;
        const int q = t % 12;
        s_w2[t] = (q < 9) ? w2[(q / 3) * 27 + (q % 3) * 9 + k] : 0.f;
    }
    if (threadIdx.x < 18) s_b[threadIdx.x] = b1[threadIdx.x];
    if (threadIdx.x < COUT) s_b2[threadIdx.x] = b2[threadIdx.x];
    __syncthreads();

    constexpr int WQ = WO / 2;  // 255
    constexpr int HQ = HO / 2;  // 255
    const int idx = blockIdx.x * 256 + threadIdx.x;
    if (idx >= BB * HQ * WQ) return;
    const int jq = idx % WQ;
    const int t1 = idx / WQ;
    const int iq = t1 % HQ;
    const int b = t1 / HQ;
    const int i = iq * 2;
    const int j = jq * 2;

    const float4* xb4 = xT + (size_t)b * HW;

    // 4x4 patch of float4 pixels covers all four 3x3 windows.
    float4 pat[4][4];
#pragma unroll
    for (int r = 0; r < 4; ++r)
#pragma unroll
        for (int col = 0; col < 4; ++col)
            pat[r][col] = xb4[(i + r) * WW + j + col];

    float acc[2][2][COUT];
#pragma unroll
    for (int di = 0; di < 2; ++di)
#pragma unroll
        for (int dj = 0; dj < 2; ++dj)
#pragma unroll
            for (int o = 0; o < COUT; ++o) acc[di][dj][o] = s_b2[o];

#pragma unroll
    for (int k = 0; k < KK; ++k) {
        const int ky = k / 3;
        const int kx = k % 3;

        // ---- conv1: offsets for the 4 pixels ----
        float dy[2][2], dx[2][2];
#pragma unroll
        for (int di = 0; di < 2; ++di)
#pragma unroll
            for (int dj = 0; dj < 2; ++dj) {
                dy[di][dj] = s_b[2 * k];
                dx[di][dj] = s_b[2 * k + 1];
            }
#pragma unroll
        for (int g = 0; g < 14; ++g) {
            const float4 wv = s_w4[k * 14 + g];
            {
                const int t2 = 2 * g;
                const int r = t2 / 9, s = (t2 % 9) / 3, c = t2 % 3;
#pragma unroll
                for (int di = 0; di < 2; ++di)
#pragma unroll
                    for (int dj = 0; dj < 2; ++dj) {
                        const float p = comp3(pat[di + r][dj + s], c);
                        dy[di][dj] += p * wv.x;
                        dx[di][dj] += p * wv.y;
                    }
            }
            if (2 * g + 1 < 27) {
                const int t2 = 2 * g + 1;
                const int r = t2 / 9, s = (t2 % 9) / 3, c = t2 % 3;
#pragma unroll
                for (int di = 0; di < 2; ++di)
#pragma unroll
                    for (int dj = 0; dj < 2; ++dj) {
                        const float p = comp3(pat[di + r][dj + s], c);
                        dy[di][dj] += p * wv.z;
                        dx[di][dj] += p * wv.w;
                    }
            }
        }

        // ---- bilinear gather + conv2 for the 4 pixels ----
        const float4* wk4 = reinterpret_cast<const float4*>(&s_w2[k * 12]);
        const float4 a = wk4[0];
        const float4 bbv = wk4[1];
        const float cw = s_w2[k * 12 + 8];

#pragma unroll
        for (int di = 0; di < 2; ++di)
#pragma unroll
            for (int dj = 0; dj < 2; ++dj) {
                const float sy = (float)(i + di + ky) + dy[di][dj];
                const float sx = (float)(j + dj + kx) + dx[di][dj];
                const float y0f = floorf(sy);
                const float x0f = floorf(sx);
                const float fy = sy - y0f;
                const float fx = sx - x0f;
                const int y0 = (int)y0f;
                const int x0 = (int)x0f;
                const int y1 = y0 + 1;
                const int x1 = x0 + 1;

                const float wy0 = ((unsigned)y0 < (unsigned)HH) ? (1.f - fy) : 0.f;
                const float wy1 = ((unsigned)y1 < (unsigned)HH) ? fy : 0.f;
                const float wx0 = ((unsigned)x0 < (unsigned)WW) ? (1.f - fx) : 0.f;
                const float wx1 = ((unsigned)x1 < (unsigned)WW) ? fx : 0.f;

                const int y0c = min(max(y0, 0), HH - 1);
                const int y1c = min(max(y1, 0), HH - 1);
                const int x0c = min(max(x0, 0), WW - 1);
                const int x1c = min(max(x1, 0), WW - 1);

                const float4 c00 = xb4[y0c * WW + x0c];
                const float4 c01 = xb4[y0c * WW + x1c];
                const float4 c10 = xb4[y1c * WW + x0c];
                const float4 c11 = xb4[y1c * WW + x1c];

                const float w00 = wy0 * wx0, w01 = wy0 * wx1;
                const float w10 = wy1 * wx0, w11 = wy1 * wx1;

                const float v0 = w00 * c00.x + w01 * c01.x + w10 * c10.x + w11 * c11.x;
                const float v1 = w00 * c00.y + w01 * c01.y + w10 * c10.y + w11 * c11.y;
                const float v2 = w00 * c00.z + w01 * c01.z + w10 * c10.z + w11 * c11.z;

                acc[di][dj][0] += a.x * v0 + a.y * v1 + a.z * v2;
                acc[di][dj][1] += a.w * v0 + bbv.x * v1 + bbv.y * v2;
                acc[di][dj][2] += bbv.z * v0 + bbv.w * v1 + cw * v2;
            }
    }

    float* ob = out + (size_t)b * COUT * HOWO;
#pragma unroll
    for (int o = 0; o < COUT; ++o)
#pragma unroll
        for (int di = 0; di < 2; ++di) {
            float2 st;
            st.x = acc[di][0][o];
            st.y = acc[di][1][o];
            *reinterpret_cast<float2*>(&ob[o * HOWO + (i + di) * WO + j]) = st;
        }
}

// ---------------- fallback: R0-style fully fused (no workspace) ----------
__global__ __launch_bounds__(256) void deform_fused_kernel(
    const float* __restrict__ x, const float* __restrict__ w1,
    const float* __restrict__ b1, const float* __restrict__ w2,
    const float* __restrict__ b2, float* __restrict__ out)
{
    __shared__ float s_w1[18 * 27];
    __shared__ float s_b1[18];
    __shared__ float s_w2[COUT * CIN * KK];
    __shared__ float s_b2[COUT];
    for (int t = threadIdx.x; t < 18 * 27; t += blockDim.x) s_w1[t] = w1[t];
    if (threadIdx.x < 18) s_b1[threadIdx.x] = b1[threadIdx.x];
    if (threadIdx.x < COUT * CIN * KK) s_w2[threadIdx.x] = w2[threadIdx.x];
    if (threadIdx.x < COUT) s_b2[threadIdx.x] = b2[threadIdx.x];
    __syncthreads();
    const int idx = blockIdx.x * blockDim.x + threadIdx.x;
    if (idx >= BB * HOWO) return;
    const int j = idx % WO;
    const int tmp = idx / WO;
    const int i = tmp % HO;
    const int b = tmp / HO;
    const float* xb = x + (size_t)b * CIN * HW;
    float patch[CIN][3][3];
#pragma unroll
    for (int c = 0; c < CIN; ++c)
#pragma unroll
        for (int r = 0; r < 3; ++r)
#pragma unroll
            for (int s = 0; s < 3; ++s)
                patch[c][r][s] = xb[c * HW + (i + r) * WW + (j + s)];
    float acc0 = s_b2[0], acc1 = s_b2[1], acc2 = s_b2[2];
#pragma unroll
    for (int k = 0; k < KK; ++k) {
        const int ky = k / 3, kx = k % 3;
        float dy = s_b1[2 * k], dx = s_b1[2 * k + 1];
        const float* wy = &s_w1[(2 * k) * 27];
        const float* wx = &s_w1[(2 * k + 1) * 27];
        int t = 0;
#pragma unroll
        for (int c = 0; c < CIN; ++c)
#pragma unroll
            for (int r = 0; r < 3; ++r)
#pragma unroll
                for (int s = 0; s < 3; ++s, ++t) {
                    const float pv = patch[c][r][s];
                    dy += pv * wy[t];
                    dx += pv * wx[t];
                }
        const float sy = (float)(i + ky) + dy;
        const float sx = (float)(j + kx) + dx;
        const float y0f = floorf(sy), x0f = floorf(sx);
        const float fy = sy - y0f, fx = sx - x0f;
        const int y0 = (int)y0f, x0 = (int)x0f;
        float v0 = 0.f, v1 = 0.f, v2 = 0.f;
#pragma unroll
        for (int cy = 0; cy < 2; ++cy) {
            const int iy = y0 + cy;
            const float wyf = cy ? fy : (1.f - fy);
            const bool vy = (iy >= 0) && (iy < HH);
            const int iyc = iy < 0 ? 0 : (iy > HH - 1 ? HH - 1 : iy);
#pragma unroll
            for (int cx = 0; cx < 2; ++cx) {
                const int ix = x0 + cx;
                const float wxf = cx ? fx : (1.f - fx);
                const bool vx = (ix >= 0) && (ix < WW);
                const int ixc = ix < 0 ? 0 : (ix > WW - 1 ? WW - 1 : ix);
                const float wgt = (vy && vx) ? (wyf * wxf) : 0.f;
                const int off = iyc * WW + ixc;
                v0 += wgt * xb[0 * HW + off];
                v1 += wgt * xb[1 * HW + off];
                v2 += wgt * xb[2 * HW + off];
            }
        }
#pragma unroll
        for (int o = 0; o < COUT; ++o) {
            const float c0 = s_w2[(o * CIN + 0) * KK + k];
            const float c1 = s_w2[(o * CIN + 1) * KK + k];
            const float c2 = s_w2[(o * CIN + 2) * KK + k];
            const float contrib = c0 * v0 + c1 * v1 + c2 * v2;
            if (o == 0) acc0 += contrib;
            else if (o == 1) acc1 += contrib;
            else acc2 += contrib;
        }
    }
    float* ob = out + (size_t)b * COUT * HOWO + (size_t)i * WO + j;
    ob[0 * HOWO] = acc0;
    ob[1 * HOWO] = acc1;
    ob[2 * HOWO] = acc2;
}

extern "C" void kernel_launch(void* const* d_in, const int* in_sizes, int n_in,
                              void* d_out, int out_size, void* d_ws, size_t ws_size,
                              hipStream_t stream) {
    const float* x  = (const float*)d_in[0];
    const float* w1 = (const float*)d_in[1];
    const float* b1 = (const float*)d_in[2];
    const float* w2 = (const float*)d_in[3];
    const float* b2 = (const float*)d_in[4];
    float* out = (float*)d_out;

    if (ws_size >= XT_BYTES) {
        float4* xT = (float4*)d_ws;
        {
            const int total = BB * HH * WW;
            repack_nhwc<<<(total + 255) / 256, 256, 0, stream>>>(x, xT);
        }
        {
            const int total = BB * (HO / 2) * (WO / 2);
            deform_fused2<<<(total + 255) / 256, 256, 0, stream>>>(
                xT, w1, b1, w2, b2, out);
        }
    } else {
        const int total = BB * HOWO;
        deform_fused_kernel<<<(total + 255) / 256, 256, 0, stream>>>(
            x, w1, b1, w2, b2, out);
    }
}

// Round 5
// 55.817 us; speedup vs baseline: 3.6814x; 3.6814x over previous
//
#include <hip/hip_runtime.h>

#define BB 4
#define CIN 3
#define HH 512
#define WW 512
#define KK 9
#define COUT 3
#define HO 510
#define WO 510
#define HW (HH * WW)
#define HOWO (HO * WO)

#define XT_BYTES ((size_t)BB * HH * WW * 4 * sizeof(float))

__device__ __forceinline__ float comp3(const float4& v, int c) {
    return c == 0 ? v.x : (c == 1 ? v.y : v.z);
}

// ---------------- kernel 1: NCHW -> NHW4 repack ----------------
__global__ __launch_bounds__(256) void repack_nhwc(
    const float* __restrict__ x, float4* __restrict__ xT)
{
    const int idx = blockIdx.x * blockDim.x + threadIdx.x;
    const int total = BB * HH * WW;
    if (idx >= total) return;
    const int b = idx / HW;
    const int p = idx - b * HW;
    const float* xb = x + (size_t)b * CIN * HW;
    float4 v;
    v.x = xb[0 * HW + p];
    v.y = xb[1 * HW + p];
    v.z = xb[2 * HW + p];
    v.w = 0.f;
    xT[idx] = v;
}

// ---------------- kernel 2: fused conv1 + gather + conv2, 2 px/thread ------
__global__ __launch_bounds__(256) void deform_fused2(
    const float4* __restrict__ xT,  // [B][H][W] (3ch + pad)
    const float* __restrict__ w1,   // [18][3][3][3]
    const float* __restrict__ b1,   // [18]
    const float* __restrict__ w2,   // [3][3][3][3]
    const float* __restrict__ b2,   // [3]
    float* __restrict__ out)        // [B][3][HO][WO]
{
    // s_w4[k*14+g] = (wy[2g], wx[2g], wy[2g+1], wx[2g+1]), t2 = r*9+s*3+c
    __shared__ float4 s_w4[KK * 14];
    __shared__ float s_b[18];
    __shared__ float s_w2[KK * 12];  // [k][12], first 9 = o*3+c
    __shared__ float s_b2[COUT];

    for (int t = threadIdx.x; t < KK * 56; t += 256) {
        const int k = t / 56;
        const int rem = t % 56;
        const int g = rem >> 2;
        const int comp = rem & 3;
        const int t2 = 2 * g + (comp >> 1);
        const int w = comp & 1;
        float val = 0.f;
        if (t2 < 27) {
            const int r = t2 / 9;
            const int s = (t2 % 9) / 3;
            const int c = t2 % 3;
            val = w1[(2 * k + w) * 27 + c * 9 + r * 3 + s];
        }
        reinterpret_cast<float*>(s_w4)[t] = val;
    }
    for (int t = threadIdx.x; t < KK * 12; t += 256) {
        const int k = t / 12;
        const int q = t % 12;
        s_w2[t] = (q < 9) ? w2[(q / 3) * 27 + (q % 3) * 9 + k] : 0.f;
    }
    if (threadIdx.x < 18) s_b[threadIdx.x] = b1[threadIdx.x];
    if (threadIdx.x < COUT) s_b2[threadIdx.x] = b2[threadIdx.x];
    __syncthreads();

    constexpr int WP = WO / 2;  // 255
    const int idx = blockIdx.x * 256 + threadIdx.x;
    if (idx >= BB * HO * WP) return;
    const int jp = idx % WP;
    const int t1 = idx / WP;
    const int i = t1 % HO;
    const int b = t1 / HO;
    const int j = jp * 2;

    const float4* xb4 = xT + (size_t)b * HW;

    // 3x4 patch of float4 pixels covers both 3x3 windows.
    float4 pat[3][4];
#pragma unroll
    for (int r = 0; r < 3; ++r)
#pragma unroll
        for (int col = 0; col < 4; ++col)
            pat[r][col] = xb4[(i + r) * WW + j + col];

    float acc00 = s_b2[0], acc01 = s_b2[1], acc02 = s_b2[2];
    float acc10 = s_b2[0], acc11 = s_b2[1], acc12 = s_b2[2];

    for (int ky = 0; ky < 3; ++ky)
        for (int kx = 0; kx < 3; ++kx) {
            const int k = ky * 3 + kx;

            // ---- conv1: offsets for both pixels ----
            float dy0 = s_b[2 * k], dx0 = s_b[2 * k + 1];
            float dy1 = dy0, dx1 = dx0;
            const float4* wk = &s_w4[k * 14];
#pragma unroll
            for (int g = 0; g < 14; ++g) {
                const float4 wv = wk[g];
                {
                    const int t2 = 2 * g;
                    const int r = t2 / 9, s = (t2 % 9) / 3, c = t2 % 3;
                    const float p0 = comp3(pat[r][s], c);
                    const float p1 = comp3(pat[r][s + 1], c);
                    dy0 += p0 * wv.x;
                    dx0 += p0 * wv.y;
                    dy1 += p1 * wv.x;
                    dx1 += p1 * wv.y;
                }
                if (2 * g + 1 < 27) {
                    const int t2 = 2 * g + 1;
                    const int r = t2 / 9, s = (t2 % 9) / 3, c = t2 % 3;
                    const float p0 = comp3(pat[r][s], c);
                    const float p1 = comp3(pat[r][s + 1], c);
                    dy0 += p0 * wv.z;
                    dx0 += p0 * wv.w;
                    dy1 += p1 * wv.z;
                    dx1 += p1 * wv.w;
                }
            }

            // ---- conv2 weights for this tap ----
            const float4* wk4 = reinterpret_cast<const float4*>(&s_w2[k * 12]);
            const float4 a = wk4[0];
            const float4 bbv = wk4[1];
            const float cw = s_w2[k * 12 + 8];

            // ---- bilinear gather + conv2, both pixels ----
#pragma unroll
            for (int p = 0; p < 2; ++p) {
                const float dy = p ? dy1 : dy0;
                const float dx = p ? dx1 : dx0;
                const float sy = (float)(i + ky) + dy;
                const float sx = (float)(j + p + kx) + dx;
                const float y0f = floorf(sy);
                const float x0f = floorf(sx);
                const float fy = sy - y0f;
                const float fx = sx - x0f;
                const int y0 = (int)y0f;
                const int x0 = (int)x0f;
                const int y1 = y0 + 1;
                const int x1 = x0 + 1;

                const float wy0 = ((unsigned)y0 < (unsigned)HH) ? (1.f - fy) : 0.f;
                const float wy1 = ((unsigned)y1 < (unsigned)HH) ? fy : 0.f;
                const float wx0 = ((unsigned)x0 < (unsigned)WW) ? (1.f - fx) : 0.f;
                const float wx1 = ((unsigned)x1 < (unsigned)WW) ? fx : 0.f;

                const int y0c = min(max(y0, 0), HH - 1);
                const int y1c = min(max(y1, 0), HH - 1);
                const int x0c = min(max(x0, 0), WW - 1);
                const int x1c = min(max(x1, 0), WW - 1);

                const float4 c00 = xb4[y0c * WW + x0c];
                const float4 c01 = xb4[y0c * WW + x1c];
                const float4 c10 = xb4[y1c * WW + x0c];
                const float4 c11 = xb4[y1c * WW + x1c];

                const float w00 = wy0 * wx0, w01 = wy0 * wx1;
                const float w10 = wy1 * wx0, w11 = wy1 * wx1;

                const float v0 = w00 * c00.x + w01 * c01.x + w10 * c10.x + w11 * c11.x;
                const float v1 = w00 * c00.y + w01 * c01.y + w10 * c10.y + w11 * c11.y;
                const float v2 = w00 * c00.z + w01 * c01.z + w10 * c10.z + w11 * c11.z;

                const float r0 = a.x * v0 + a.y * v1 + a.z * v2;
                const float r1 = a.w * v0 + bbv.x * v1 + bbv.y * v2;
                const float r2 = bbv.z * v0 + bbv.w * v1 + cw * v2;
                if (p == 0) {
                    acc00 += r0; acc01 += r1; acc02 += r2;
                } else {
                    acc10 += r0; acc11 += r1; acc12 += r2;
                }
            }
        }

    float* ob = out + (size_t)b * COUT * HOWO + (size_t)i * WO + j;
    {
        float2 st;
        st.x = acc00; st.y = acc10;
        *reinterpret_cast<float2*>(&ob[0 * HOWO]) = st;
        st.x = acc01; st.y = acc11;
        *reinterpret_cast<float2*>(&ob[1 * HOWO]) = st;
        st.x = acc02; st.y = acc12;
        *reinterpret_cast<float2*>(&ob[2 * HOWO]) = st;
    }
}

// ---------------- fallback: R0-style fully fused (no workspace) ----------
__global__ __launch_bounds__(256) void deform_fused_kernel(
    const float* __restrict__ x, const float* __restrict__ w1,
    const float* __restrict__ b1, const float* __restrict__ w2,
    const float* __restrict__ b2, float* __restrict__ out)
{
    __shared__ float s_w1[18 * 27];
    __shared__ float s_b1[18];
    __shared__ float s_w2[COUT * CIN * KK];
    __shared__ float s_b2[COUT];
    for (int t = threadIdx.x; t < 18 * 27; t += blockDim.x) s_w1[t] = w1[t];
    if (threadIdx.x < 18) s_b1[threadIdx.x] = b1[threadIdx.x];
    if (threadIdx.x < COUT * CIN * KK) s_w2[threadIdx.x] = w2[threadIdx.x];
    if (threadIdx.x < COUT) s_b2[threadIdx.x] = b2[threadIdx.x];
    __syncthreads();
    const int idx = blockIdx.x * blockDim.x + threadIdx.x;
    if (idx >= BB * HOWO) return;
    const int j = idx % WO;
    const int tmp = idx / WO;
    const int i = tmp % HO;
    const int b = tmp / HO;
    const float* xb = x + (size_t)b * CIN * HW;
    float patch[CIN][3][3];
#pragma unroll
    for (int c = 0; c < CIN; ++c)
#pragma unroll
        for (int r = 0; r < 3; ++r)
#pragma unroll
            for (int s = 0; s < 3; ++s)
                patch[c][r][s] = xb[c * HW + (i + r) * WW + (j + s)];
    float acc0 = s_b2[0], acc1 = s_b2[1], acc2 = s_b2[2];
#pragma unroll
    for (int k = 0; k < KK; ++k) {
        const int ky = k / 3, kx = k % 3;
        float dy = s_b1[2 * k], dx = s_b1[2 * k + 1];
        const float* wy = &s_w1[(2 * k) * 27];
        const float* wx = &s_w1[(2 * k + 1) * 27];
        int t = 0;
#pragma unroll
        for (int c = 0; c < CIN; ++c)
#pragma unroll
            for (int r = 0; r < 3; ++r)
#pragma unroll
                for (int s = 0; s < 3; ++s, ++t) {
                    const float pv = patch[c][r][s];
                    dy += pv * wy[t];
                    dx += pv * wx[t];
                }
        const float sy = (float)(i + ky) + dy;
        const float sx = (float)(j + kx) + dx;
        const float y0f = floorf(sy), x0f = floorf(sx);
        const float fy = sy - y0f, fx = sx - x0f;
        const int y0 = (int)y0f, x0 = (int)x0f;
        float v0 = 0.f, v1 = 0.f, v2 = 0.f;
#pragma unroll
        for (int cy = 0; cy < 2; ++cy) {
            const int iy = y0 + cy;
            const float wyf = cy ? fy : (1.f - fy);
            const bool vy = (iy >= 0) && (iy < HH);
            const int iyc = iy < 0 ? 0 : (iy > HH - 1 ? HH - 1 : iy);
#pragma unroll
            for (int cx = 0; cx < 2; ++cx) {
                const int ix = x0 + cx;
                const float wxf = cx ? fx : (1.f - fx);
                const bool vx = (ix >= 0) && (ix < WW);
                const int ixc = ix < 0 ? 0 : (ix > WW - 1 ? WW - 1 : ix);
                const float wgt = (vy && vx) ? (wyf * wxf) : 0.f;
                const int off = iyc * WW + ixc;
                v0 += wgt * xb[0 * HW + off];
                v1 += wgt * xb[1 * HW + off];
                v2 += wgt * xb[2 * HW + off];
            }
        }
#pragma unroll
        for (int o = 0; o < COUT; ++o) {
            const float c0 = s_w2[(o * CIN + 0) * KK + k];
            const float c1 = s_w2[(o * CIN + 1) * KK + k];
            const float c2 = s_w2[(o * CIN + 2) * KK + k];
            const float contrib = c0 * v0 + c1 * v1 + c2 * v2;
            if (o == 0) acc0 += contrib;
            else if (o == 1) acc1 += contrib;
            else acc2 += contrib;
        }
    }
    float* ob = out + (size_t)b * COUT * HOWO + (size_t)i * WO + j;
    ob[0 * HOWO] = acc0;
    ob[1 * HOWO] = acc1;
    ob[2 * HOWO] = acc2;
}

extern "C" void kernel_launch(void* const* d_in, const int* in_sizes, int n_in,
                              void* d_out, int out_size, void* d_ws, size_t ws_size,
                              hipStream_t stream) {
    const float* x  = (const float*)d_in[0];
    const float* w1 = (const float*)d_in[1];
    const float* b1 = (const float*)d_in[2];
    const float* w2 = (const float*)d_in[3];
    const float* b2 = (const float*)d_in[4];
    float* out = (float*)d_out;

    if (ws_size >= XT_BYTES) {
        float4* xT = (float4*)d_ws;
        {
            const int total = BB * HH * WW;
            repack_nhwc<<<(total + 255) / 256, 256, 0, stream>>>(x, xT);
        }
        {
            const int total = BB * HO * (WO / 2);
            deform_fused2<<<(total + 255) / 256, 256, 0, stream>>>(
                xT, w1, b1, w2, b2, out);
        }
    } else {
        const int total = BB * HOWO;
        deform_fused_kernel<<<(total + 255) / 256, 256, 0, stream>>>(
            x, w1, b1, w2, b2, out);
    }
}

// Round 7
// 52.650 us; speedup vs baseline: 3.9028x; 1.0601x over previous
//
#include <hip/hip_runtime.h>

#define BB 4
#define CIN 3
#define HH 512
#define WW 512
#define KK 9
#define COUT 3
#define HO 510
#define WO 510
#define HW (HH * WW)
#define HOWO (HO * WO)

// padded NHWC buffer: rows -3..514, cols -3..516 -> [518][520], origin (3,3)
#define PR 518
#define PC 520
#define PAD 3
#define XP_BYTES ((size_t)BB * PR * PC * 4 * sizeof(float))

typedef __fp16 h2 __attribute__((ext_vector_type(2)));

__device__ __forceinline__ h2 pkrtz(float a, float b) {
    return __builtin_amdgcn_cvt_pkrtz(a, b);
}
__device__ __forceinline__ float fdot2f(h2 a, h2 b, float c) {
    return __builtin_amdgcn_fdot2(a, b, c, false);
}
__device__ __forceinline__ h2 uint_as_h2(unsigned u) {
    return __builtin_bit_cast(h2, u);
}
__device__ __forceinline__ unsigned h2_as_uint(h2 h) {
    return __builtin_bit_cast(unsigned, h);
}
__device__ __forceinline__ float comp3(const float4& v, int c) {
    return c == 0 ? v.x : (c == 1 ? v.y : v.z);
}
// w1 element for channel ch at t2 = r*9 + s*3 + c (0 if t2 >= 27)
__device__ __forceinline__ float w1f(const float* w1, int ch, int t2) {
    if (t2 >= 27) return 0.f;
    const int r = t2 / 9, s = (t2 % 9) / 3, c = t2 % 3;
    return w1[ch * 27 + c * 9 + r * 3 + s];
}

// ---------------- kernel 1: NCHW -> padded NHW4 repack ----------------
__global__ __launch_bounds__(256) void repack_pad(
    const float* __restrict__ x, float4* __restrict__ xp)
{
    const int idx = blockIdx.x * blockDim.x + threadIdx.x;
    const int total = BB * PR * PC;
    if (idx >= total) return;
    const int b = idx / (PR * PC);
    const int rem = idx - b * (PR * PC);
    const int y = rem / PC;
    const int xc = rem - y * PC;
    const int ys = y - PAD;
    const int xs = xc - PAD;
    float4 v = make_float4(0.f, 0.f, 0.f, 0.f);
    if ((unsigned)ys < (unsigned)HH && (unsigned)xs < (unsigned)WW) {
        const float* xb = x + (size_t)b * CIN * HW;
        const int p = ys * WW + xs;
        v.x = xb[p];
        v.y = xb[HW + p];
        v.z = xb[2 * HW + p];
    }
    xp[idx] = v;
}

// ---------------- kernel 2: fused conv1(fdot2) + gather + conv2 ------------
__global__ __launch_bounds__(256) void deform_fused3(
    const float4* __restrict__ xp,  // [B][PR][PC] padded NHWC
    const float* __restrict__ w1,   // [18][3][3][3]
    const float* __restrict__ b1,   // [18]
    const float* __restrict__ w2,   // [3][3][3][3]
    const float* __restrict__ b2,   // [3]
    float* __restrict__ out)        // [B][3][HO][WO]
{
    // conv1 weights packed f16: s_w1h[k*7+gg] = {wy(4gg,4gg+1), wx(..),
    // wy(4gg+2,4gg+3), wx(..)}; t2 = r*9+s*3+c, t2=27 padded 0.
    __shared__ uint4 s_w1h[KK * 7];
    __shared__ float s_b[18];
    __shared__ float s_w2[KK * 12];  // [k][12], first 9 = o*3+c
    __shared__ float s_b2[COUT];

    if (threadIdx.x < KK * 7) {
        const int k = threadIdx.x / 7;
        const int gg = threadIdx.x % 7;
        float wy[4], wx[4];
#pragma unroll
        for (int q = 0; q < 4; ++q) {
            const int t2 = 4 * gg + q;
            wy[q] = w1f(w1, 2 * k, t2);
            wx[q] = w1f(w1, 2 * k + 1, t2);
        }
        uint4 u;
        u.x = h2_as_uint(pkrtz(wy[0], wy[1]));
        u.y = h2_as_uint(pkrtz(wx[0], wx[1]));
        u.z = h2_as_uint(pkrtz(wy[2], wy[3]));
        u.w = h2_as_uint(pkrtz(wx[2], wx[3]));
        s_w1h[threadIdx.x] = u;
    }
    for (int t = threadIdx.x; t < KK * 12; t += 256) {
        const int k = t / 12;
        const int q = t % 12;
        s_w2[t] = (q < 9) ? w2[(q / 3) * 27 + (q % 3) * 9 + k] : 0.f;
    }
    if (threadIdx.x < 18) s_b[threadIdx.x] = b1[threadIdx.x];
    if (threadIdx.x < COUT) s_b2[threadIdx.x] = b2[threadIdx.x];
    __syncthreads();

    constexpr int WP = WO / 2;  // 255
    const int idx = blockIdx.x * 256 + threadIdx.x;
    if (idx >= BB * HO * WP) return;
    const int jp = idx % WP;
    const int t1 = idx / WP;
    const int i = t1 % HO;
    const int b = t1 / HO;
    const int j = jp * 2;

    const float4* xb4 = xp + (size_t)b * (PR * PC);

    // 3x4 patch (image coords rows i..i+2, cols j..j+3) from padded buffer.
    float4 pat[3][4];
#pragma unroll
    for (int r = 0; r < 3; ++r)
#pragma unroll
        for (int col = 0; col < 4; ++col)
            pat[r][col] = xb4[(i + r + PAD) * PC + (j + col + PAD)];

    // f16-pair packed patch per pixel over t2: ph[g] = (val[2g], val[2g+1])
    h2 ph0[14], ph1[14];
#pragma unroll
    for (int g = 0; g < 14; ++g) {
        const int ta = 2 * g;
        const int ra = ta / 9, sa = (ta % 9) / 3, ca = ta % 3;
        const float a0 = comp3(pat[ra][sa], ca);
        const float a1 = comp3(pat[ra][sa + 1], ca);
        float b0 = 0.f, b1v = 0.f;
        if (2 * g + 1 < 27) {
            const int tb = 2 * g + 1;
            const int rb = tb / 9, sb = (tb % 9) / 3, cb = tb % 3;
            b0 = comp3(pat[rb][sb], cb);
            b1v = comp3(pat[rb][sb + 1], cb);
        }
        ph0[g] = pkrtz(a0, b0);
        ph1[g] = pkrtz(a1, b1v);
    }

    float acc00 = s_b2[0], acc01 = s_b2[1], acc02 = s_b2[2];
    float acc10 = s_b2[0], acc11 = s_b2[1], acc12 = s_b2[2];

    const float fi3 = (float)i + (float)PAD;
    const float fj3 = (float)j + (float)PAD;

    for (int ky = 0; ky < 3; ++ky)
        for (int kx = 0; kx < 3; ++kx) {
            const int k = ky * 3 + kx;

            // ---- conv1 via fdot2 (f32 accumulate), 8 independent chains ----
            float ay0 = 0.f, ax0 = 0.f, ay1 = 0.f, ax1 = 0.f;
            float by0 = 0.f, bx0 = 0.f, by1 = 0.f, bx1 = 0.f;
            const uint4* wk = &s_w1h[k * 7];
#pragma unroll
            for (int gg = 0; gg < 7; ++gg) {
                const uint4 w = wk[gg];
                const h2 wyA = uint_as_h2(w.x);
                const h2 wxA = uint_as_h2(w.y);
                const h2 wyB = uint_as_h2(w.z);
                const h2 wxB = uint_as_h2(w.w);
                ay0 = fdot2f(wyA, ph0[2 * gg], ay0);
                ax0 = fdot2f(wxA, ph0[2 * gg], ax0);
                ay1 = fdot2f(wyA, ph1[2 * gg], ay1);
                ax1 = fdot2f(wxA, ph1[2 * gg], ax1);
                by0 = fdot2f(wyB, ph0[2 * gg + 1], by0);
                bx0 = fdot2f(wxB, ph0[2 * gg + 1], bx0);
                by1 = fdot2f(wyB, ph1[2 * gg + 1], by1);
                bx1 = fdot2f(wxB, ph1[2 * gg + 1], bx1);
            }
            const float dy0 = s_b[2 * k] + (ay0 + by0);
            const float dx0 = s_b[2 * k + 1] + (ax0 + bx0);
            const float dy1 = s_b[2 * k] + (ay1 + by1);
            const float dx1 = s_b[2 * k + 1] + (ax1 + bx1);

            // ---- conv2 weights for this tap ----
            const float4* wk4 = reinterpret_cast<const float4*>(&s_w2[k * 12]);
            const float4 a = wk4[0];
            const float4 bbv = wk4[1];
            const float cw = s_w2[k * 12 + 8];

            // ---- gather + conv2, both pixels; padded coords always valid ----
#pragma unroll
            for (int p = 0; p < 2; ++p) {
                const float dy = p ? dy1 : dy0;
                const float dx = p ? dx1 : dx0;
                const float syp = fi3 + (float)ky + dy;  // > 0 always
                const float sxp = fj3 + (float)(p + kx) + dx;
                const int y0 = (int)syp;  // trunc == floor (positive)
                const int x0 = (int)sxp;
                const float fy = syp - (float)y0;
                const float fx = sxp - (float)x0;

                const int a00 = y0 * PC + x0;
                const float4 c00 = xb4[a00];
                const float4 c01 = xb4[a00 + 1];
                const float4 c10 = xb4[a00 + PC];
                const float4 c11 = xb4[a00 + PC + 1];

                const float wy0 = 1.f - fy, wx0 = 1.f - fx;
                const float w00 = wy0 * wx0, w01 = wy0 * fx;
                const float w10 = fy * wx0, w11 = fy * fx;

                const float v0 = w00 * c00.x + w01 * c01.x + w10 * c10.x + w11 * c11.x;
                const float v1 = w00 * c00.y + w01 * c01.y + w10 * c10.y + w11 * c11.y;
                const float v2 = w00 * c00.z + w01 * c01.z + w10 * c10.z + w11 * c11.z;

                const float r0 = a.x * v0 + a.y * v1 + a.z * v2;
                const float r1 = a.w * v0 + bbv.x * v1 + bbv.y * v2;
                const float r2 = bbv.z * v0 + bbv.w * v1 + cw * v2;
                if (p == 0) {
                    acc00 += r0; acc01 += r1; acc02 += r2;
                } else {
                    acc10 += r0; acc11 += r1; acc12 += r2;
                }
            }
        }

    float* ob = out + (size_t)b * COUT * HOWO + (size_t)i * WO + j;
    {
        float2 st;
        st.x = acc00; st.y = acc10;
        *reinterpret_cast<float2*>(&ob[0 * HOWO]) = st;
        st.x = acc01; st.y = acc11;
        *reinterpret_cast<float2*>(&ob[1 * HOWO]) = st;
        st.x = acc02; st.y = acc12;
        *reinterpret_cast<float2*>(&ob[2 * HOWO]) = st;
    }
}

// ---------------- fallback: R0-style fully fused (no workspace) ----------
__global__ __launch_bounds__(256) void deform_fused_kernel(
    const float* __restrict__ x, const float* __restrict__ w1,
    const float* __restrict__ b1, const float* __restrict__ w2,
    const float* __restrict__ b2, float* __restrict__ out)
{
    __shared__ float s_w1[18 * 27];
    __shared__ float s_b1[18];
    __shared__ float s_w2[COUT * CIN * KK];
    __shared__ float s_b2[COUT];
    for (int t = threadIdx.x; t < 18 * 27; t += blockDim.x) s_w1[t] = w1[t];
    if (threadIdx.x < 18) s_b1[threadIdx.x] = b1[threadIdx.x];
    if (threadIdx.x < COUT * CIN * KK) s_w2[threadIdx.x] = w2[threadIdx.x];
    if (threadIdx.x < COUT) s_b2[threadIdx.x] = b2[threadIdx.x];
    __syncthreads();
    const int idx = blockIdx.x * blockDim.x + threadIdx.x;
    if (idx >= BB * HOWO) return;
    const int j = idx % WO;
    const int tmp = idx / WO;
    const int i = tmp % HO;
    const int b = tmp / HO;
    const float* xb = x + (size_t)b * CIN * HW;
    float patch[CIN][3][3];
#pragma unroll
    for (int c = 0; c < CIN; ++c)
#pragma unroll
        for (int r = 0; r < 3; ++r)
#pragma unroll
            for (int s = 0; s < 3; ++s)
                patch[c][r][s] = xb[c * HW + (i + r) * WW + (j + s)];
    float acc0 = s_b2[0], acc1 = s_b2[1], acc2 = s_b2[2];
#pragma unroll
    for (int k = 0; k < KK; ++k) {
        const int ky = k / 3, kx = k % 3;
        float dy = s_b1[2 * k], dx = s_b1[2 * k + 1];
        const float* wy = &s_w1[(2 * k) * 27];
        const float* wx = &s_w1[(2 * k + 1) * 27];
        int t = 0;
#pragma unroll
        for (int c = 0; c < CIN; ++c)
#pragma unroll
            for (int r = 0; r < 3; ++r)
#pragma unroll
                for (int s = 0; s < 3; ++s, ++t) {
                    const float pv = patch[c][r][s];
                    dy += pv * wy[t];
                    dx += pv * wx[t];
                }
        const float sy = (float)(i + ky) + dy;
        const float sx = (float)(j + kx) + dx;
        const float y0f = floorf(sy), x0f = floorf(sx);
        const float fy = sy - y0f, fx = sx - x0f;
        const int y0 = (int)y0f, x0 = (int)x0f;
        float v0 = 0.f, v1 = 0.f, v2 = 0.f;
#pragma unroll
        for (int cy = 0; cy < 2; ++cy) {
            const int iy = y0 + cy;
            const float wyf = cy ? fy : (1.f - fy);
            const bool vy = (iy >= 0) && (iy < HH);
            const int iyc = iy < 0 ? 0 : (iy > HH - 1 ? HH - 1 : iy);
#pragma unroll
            for (int cx = 0; cx < 2; ++cx) {
                const int ix = x0 + cx;
                const float wxf = cx ? fx : (1.f - fx);
                const bool vx = (ix >= 0) && (ix < WW);
                const int ixc = ix < 0 ? 0 : (ix > WW - 1 ? WW - 1 : ix);
                const float wgt = (vy && vx) ? (wyf * wxf) : 0.f;
                const int off = iyc * WW + ixc;
                v0 += wgt * xb[0 * HW + off];
                v1 += wgt * xb[1 * HW + off];
                v2 += wgt * xb[2 * HW + off];
            }
        }
#pragma unroll
        for (int o = 0; o < COUT; ++o) {
            const float c0 = s_w2[(o * CIN + 0) * KK + k];
            const float c1 = s_w2[(o * CIN + 1) * KK + k];
            const float c2 = s_w2[(o * CIN + 2) * KK + k];
            const float contrib = c0 * v0 + c1 * v1 + c2 * v2;
            if (o == 0) acc0 += contrib;
            else if (o == 1) acc1 += contrib;
            else acc2 += contrib;
        }
    }
    float* ob = out + (size_t)b * COUT * HOWO + (size_t)i * WO + j;
    ob[0 * HOWO] = acc0;
    ob[1 * HOWO] = acc1;
    ob[2 * HOWO] = acc2;
}

extern "C" void kernel_launch(void* const* d_in, const int* in_sizes, int n_in,
                              void* d_out, int out_size, void* d_ws, size_t ws_size,
                              hipStream_t stream) {
    const float* x  = (const float*)d_in[0];
    const float* w1 = (const float*)d_in[1];
    const float* b1 = (const float*)d_in[2];
    const float* w2 = (const float*)d_in[3];
    const float* b2 = (const float*)d_in[4];
    float* out = (float*)d_out;

    if (ws_size >= XP_BYTES) {
        float4* xp = (float4*)d_ws;
        {
            const int total = BB * PR * PC;
            repack_pad<<<(total + 255) / 256, 256, 0, stream>>>(x, xp);
        }
        {
            const int total = BB * HO * (WO / 2);
            deform_fused3<<<(total + 255) / 256, 256, 0, stream>>>(
                xp, w1, b1, w2, b2, out);
        }
    } else {
        const int total = BB * HOWO;
        deform_fused_kernel<<<(total + 255) / 256, 256, 0, stream>>>(
            x, w1, b1, w2, b2, out);
    }
}